// Round 4
// baseline (246.487 us; speedup 1.0000x reference)
//
#include <hip/hip_runtime.h>

// QuantizedTopKSparsity on (8192, 4096) f32.
// Math collapse: gamma = rowmax(|x|) => |x/(gamma+eps)| < 1, so
// x_q = round(x/(gamma+eps)) in {-1,0,1}; abs_q in {0,1}; top-k thresh is 0
// or 1, and either way x_q * mask == x_q.  Output = rintf(x/(gamma+1e-6f)).
//
// R4 structure: TWO STREAMING KERNELS (dependency removed from hot path).
//   A: per-row absmax -> gamma[] in d_ws. Pure read+reduce.
//   B: out = rint(x/(gamma[row]+eps)). Copy-shaped elementwise stream;
//      gamma is a wave-uniform scalar load. No reduce, no barrier, low VGPR.
// R0/R3 post-mortem: any kernel with read->reduce->write serialized per wave
// plateaus at ~80us / 2.4 TB/s regardless of wave shape; compiler was already
// two-phasing (VGPR=56 < 64 needed). Make the phases explicit and separately
// streamable.

#define ROWS 8192
#define ROW_D 4096
#define EPS_Q 1e-6f

typedef float v4f __attribute__((ext_vector_type(4)));

// ---- Kernel A: gamma[row] = max|x[row,:]| ----  (one wave per row)
__global__ __launch_bounds__(256) void rowmax_kernel(const float* __restrict__ x,
                                                     float* __restrict__ gamma) {
    const int wave = threadIdx.x >> 6;
    const int lane = threadIdx.x & 63;
    const long long row = (long long)blockIdx.x * 4 + wave;
    const v4f* __restrict__ xr = reinterpret_cast<const v4f*>(x + row * (long long)ROW_D);

    float m = 0.0f;
#pragma unroll
    for (int i = 0; i < 16; ++i) {
        v4f v = xr[lane + 64 * i];
        m = fmaxf(m, fmaxf(fmaxf(fabsf(v.x), fabsf(v.y)),
                           fmaxf(fabsf(v.z), fabsf(v.w))));
    }
#pragma unroll
    for (int off = 32; off; off >>= 1) m = fmaxf(m, __shfl_xor(m, off));
    if (lane == 0) gamma[row] = m;
}

// ---- Kernel B: out = rint(x / (gamma[row]+eps)) ----  (one block per row)
__global__ __launch_bounds__(256) void quant_kernel(const float* __restrict__ x,
                                                    const float* __restrict__ gamma,
                                                    float* __restrict__ out) {
    const long long row = blockIdx.x;
    const float denom = gamma[row] + EPS_Q;  // block-uniform -> scalar load
    const v4f* __restrict__ xr = reinterpret_cast<const v4f*>(x + row * (long long)ROW_D);
    v4f* __restrict__ orow = reinterpret_cast<v4f*>(out + row * (long long)ROW_D);
    const int t = threadIdx.x;

    // rintf = round-half-even (matches np.round); true IEEE '/' so boundary
    // cases match the numpy reference exactly.
#pragma unroll
    for (int i = 0; i < 4; ++i) {
        v4f v = xr[t + 256 * i];
        v4f o;
        o.x = rintf(v.x / denom);
        o.y = rintf(v.y / denom);
        o.z = rintf(v.z / denom);
        o.w = rintf(v.w / denom);
        orow[t + 256 * i] = o;
    }
}

extern "C" void kernel_launch(void* const* d_in, const int* in_sizes, int n_in,
                              void* d_out, int out_size, void* d_ws, size_t ws_size,
                              hipStream_t stream) {
    const float* x = (const float*)d_in[0];
    float* out = (float*)d_out;
    float* gamma = (float*)d_ws;  // 8192 floats = 32 KiB scratch

    const int rows = in_sizes[0] / ROW_D;  // 8192
    rowmax_kernel<<<rows / 4, 256, 0, stream>>>(x, gamma);
    quant_kernel<<<rows, 256, 0, stream>>>(x, gamma, out);
}

// Round 5
// 245.853 us; speedup vs baseline: 1.0026x; 1.0026x over previous
//
#include <hip/hip_runtime.h>

// QuantizedTopKSparsity on (8192, 4096) f32.
// Math collapse: gamma = rowmax(|x|) => |x/(gamma+eps)| < 1, so
// x_q = round(x/(gamma+eps)) in {-1,0,1}; abs_q in {0,1}; top-k thresh is 0
// or 1, and either way x_q * mask == x_q.  Output = rintf(x/(gamma+1e-6f)).
//
// R5 structure: rowmax (one wave/row, pure read) + quant as a BLIT-SHAPED
// grid-stride stream (the 6.3 TB/s float4-copy pattern): 2048x256, 16
// independent iterations/thread, row index = v4index >> 10, NT stores so the
// streaming output doesn't evict the L3-resident input. R0-R4 post-mortem:
// per-row block/wave structures all plateau at ~2.5-3.2 TB/s while the
// harness blits hit 6.7 TB/s on the same chip -- shape, not BW, is the cap
// under test.

#define ROWS 8192
#define ROW_D 4096
#define EPS_Q 1e-6f
#define QBLOCKS 2048
#define QTHREADS 256

typedef float v4f __attribute__((ext_vector_type(4)));

// ---- Kernel A: gamma[row] = max|x[row,:]| ----  (one wave per row)
__global__ __launch_bounds__(256) void rowmax_kernel(const float* __restrict__ x,
                                                     float* __restrict__ gamma) {
    const int wave = threadIdx.x >> 6;
    const int lane = threadIdx.x & 63;
    const long long row = (long long)blockIdx.x * 4 + wave;
    const v4f* __restrict__ xr = reinterpret_cast<const v4f*>(x + row * (long long)ROW_D);

    float m = 0.0f;
#pragma unroll
    for (int i = 0; i < 16; ++i) {
        v4f v = xr[lane + 64 * i];
        m = fmaxf(m, fmaxf(fmaxf(fabsf(v.x), fabsf(v.y)),
                           fmaxf(fabsf(v.z), fabsf(v.w))));
    }
#pragma unroll
    for (int off = 32; off; off >>= 1) m = fmaxf(m, __shfl_xor(m, off));
    if (lane == 0) gamma[row] = m;
}

// ---- Kernel B: out[i] = rint(x[i] / (gamma[i>>10]+eps)) ----
// Exact blit shape: grid-stride over 8M v4 elements, coalesced, unrolled.
__global__ __launch_bounds__(QTHREADS) void quant_kernel(const float* __restrict__ x,
                                                         const float* __restrict__ gamma,
                                                         float* __restrict__ out) {
    const v4f* __restrict__ xv = reinterpret_cast<const v4f*>(x);
    v4f* __restrict__ ov = reinterpret_cast<v4f*>(out);
    const int tid = blockIdx.x * QTHREADS + threadIdx.x;
    // 8192*4096/4 = 8388608 v4; stride 2048*256 = 524288 -> exactly 16 iters.
#pragma unroll 4
    for (int j = 0; j < 16; ++j) {
        const int i = tid + j * (QBLOCKS * QTHREADS);
        const float denom = gamma[i >> 10] + EPS_Q;  // 1024 v4 per row
        v4f v = xv[i];
        v4f o;
        // rintf = round-half-even (matches np.round); true IEEE '/' so
        // boundary cases match the numpy reference exactly.
        o.x = rintf(v.x / denom);
        o.y = rintf(v.y / denom);
        o.z = rintf(v.z / denom);
        o.w = rintf(v.w / denom);
        __builtin_nontemporal_store(o, &ov[i]);
    }
}

extern "C" void kernel_launch(void* const* d_in, const int* in_sizes, int n_in,
                              void* d_out, int out_size, void* d_ws, size_t ws_size,
                              hipStream_t stream) {
    const float* x = (const float*)d_in[0];
    float* out = (float*)d_out;
    float* gamma = (float*)d_ws;  // 8192 floats = 32 KiB scratch

    const int rows = in_sizes[0] / ROW_D;  // 8192
    rowmax_kernel<<<rows / 4, 256, 0, stream>>>(x, gamma);
    quant_kernel<<<QBLOCKS, QTHREADS, 0, stream>>>(x, gamma, out);
}

// Round 6
// 220.549 us; speedup vs baseline: 1.1176x; 1.1147x over previous
//
#include <hip/hip_runtime.h>

// QuantizedTopKSparsity on (8192, 4096) f32.
// Math collapse: gamma = rowmax(|x|) => |x/(gamma+eps)| < 1, so
// x_q = round(x/(gamma+eps)) in {-1,0,1}; abs_q in {0,1}; top-k thresh is 0
// or 1, and either way x_q * mask == x_q.  Output = rintf(x/(gamma+1e-6f)).
//
// R6 structure: FUSED single-pass (traffic floor 256 MB), one WAVE per row,
// no __syncthreads, semi-persistent grid (1024 blocks; each wave does 2 rows
// sequentially) to kill block churn, __launch_bounds__(256,4) so the 128-VGPR
// budget lets the 16xv4f row stay in registers (R3's silent reload was the
// default-occupancy 64-VGPR cap). NT load + NT store: neither stream is
// re-read, keep them from thrashing L2/L3.

#define ROWS 8192
#define ROW_D 4096
#define BLOCK 256
#define GRID 1024           // 4096 waves; each wave: row w and row w+4096
#define VEC_PER_LANE 16     // 4096 / 64 lanes / 4 floats
#define EPS_Q 1e-6f

typedef float v4f __attribute__((ext_vector_type(4)));

__device__ __forceinline__ void do_row(const v4f* __restrict__ xr,
                                       v4f* __restrict__ orow, int lane) {
    v4f v[VEC_PER_LANE];
#pragma unroll
    for (int i = 0; i < VEC_PER_LANE; ++i)
        v[i] = __builtin_nontemporal_load(&xr[lane + 64 * i]);

    float m = 0.0f;
#pragma unroll
    for (int i = 0; i < VEC_PER_LANE; ++i)
        m = fmaxf(m, fmaxf(fmaxf(fabsf(v[i].x), fabsf(v[i].y)),
                           fmaxf(fabsf(v[i].z), fabsf(v[i].w))));

    // Wave-64 butterfly max reduce -- no LDS, no barrier.
#pragma unroll
    for (int off = 32; off; off >>= 1) m = fmaxf(m, __shfl_xor(m, off));

    const float denom = m + EPS_Q;

    // rintf = round-half-even (matches np.round); true IEEE '/' so boundary
    // cases match the numpy reference exactly.
#pragma unroll
    for (int i = 0; i < VEC_PER_LANE; ++i) {
        v4f o;
        o.x = rintf(v[i].x / denom);
        o.y = rintf(v[i].y / denom);
        o.z = rintf(v[i].z / denom);
        o.w = rintf(v[i].w / denom);
        __builtin_nontemporal_store(o, &orow[lane + 64 * i]);
    }
}

__global__ __launch_bounds__(BLOCK, 4) void qtern_kernel(const float* __restrict__ x,
                                                         float* __restrict__ out) {
    const int wave = threadIdx.x >> 6;
    const int lane = threadIdx.x & 63;
    const int wid = blockIdx.x * (BLOCK / 64) + wave;  // 0..4095

#pragma unroll
    for (int r = 0; r < 2; ++r) {
        const long long row = wid + r * 4096;
        do_row(reinterpret_cast<const v4f*>(x + row * (long long)ROW_D),
               reinterpret_cast<v4f*>(out + row * (long long)ROW_D), lane);
    }
}

extern "C" void kernel_launch(void* const* d_in, const int* in_sizes, int n_in,
                              void* d_out, int out_size, void* d_ws, size_t ws_size,
                              hipStream_t stream) {
    const float* x = (const float*)d_in[0];
    float* out = (float*)d_out;
    qtern_kernel<<<GRID, BLOCK, 0, stream>>>(x, out);
}